// Round 1
// baseline (348.297 us; speedup 1.0000x reference)
//
#include <hip/hip_runtime.h>

// ---------------- problem constants ----------------
// Inputs float32; d_out float32. Concat: fc, conv, flat, rnn.
#define FEAT 11664           // 16 * 27 * 27
#define OFF_FC   0u
#define OFF_CONV 4096u
#define OFF_FLAT 23891968u   // 4096 + 2048*11664
#define OFF_RNN  47779840u   // OFF_FLAT + 2048*11664

static __device__ __forceinline__ unsigned short f2bf(float f) {
    unsigned int u = __float_as_uint(f);
    u += 0x7FFFu + ((u >> 16) & 1u);       // round-to-nearest-even
    return (unsigned short)(u >> 16);
}

// ---------------- K1: conv + bias -> out_conv ; relu -> out_flat ----------------
// grid = 2048 frames (b*64+t), block = 128 = (kg 0..3)*(r 0..31, active r<27).
// Epilogue v2: stage the FULL 16x729 frame tile in LDS once (aliased over dead
// xs/wls), then a single coalesced float4 store phase for both streams.
// 2 barriers instead of 8; 4x fewer store instructions; no per-chunk vmcnt drain.
__global__ __launch_bounds__(128) void k_conv(const float* __restrict__ x,
                                              const float* __restrict__ cw,
                                              const float* __restrict__ cb,
                                              float* __restrict__ out)
{
    __shared__ __align__(16) float smem[11664];  // xs(2304)+wls(1152) compute; ot(11664) epilogue
    __shared__ float bls[16];
    float* xs  = smem;          // [ch(2)][row(32)][col(36 padded)]
    float* wls = smem + 2304;   // [ch*36 + i*6 + j][k(16)]
    float* ot  = smem;          // [k(16)][r(27)][c(27)] full-frame epilogue tile
    const int tid = threadIdx.x;
    const int frame = blockIdx.x;

    const float4* xg = (const float4*)(x + (size_t)frame * 2048);
    for (int c0 = tid; c0 < 512; c0 += 128) {
        float4 v = xg[c0];
        int e0 = c0 * 4;
        int ch = e0 >> 10, rem = e0 & 1023, row = rem >> 5, col = rem & 31;
        float* dst = &xs[ch * 1152 + row * 36 + col];
        dst[0] = v.x; dst[1] = v.y; dst[2] = v.z; dst[3] = v.w;
    }
    for (int idx = tid; idx < 1152; idx += 128) {
        int k = idx / 72;
        int rem = idx - k * 72;
        wls[rem * 16 + k] = cw[idx];
    }
    if (tid < 16) bls[tid] = cb[tid];
    __syncthreads();

    const int kg = tid >> 5;
    const int r  = tid & 31;
    float acc[4][27];
    if (r < 27) {
        #pragma unroll
        for (int kk = 0; kk < 4; ++kk)
            #pragma unroll
            for (int c = 0; c < 27; ++c) acc[kk][c] = 0.f;

        for (int ch = 0; ch < 2; ++ch) {
            for (int i = 0; i < 6; ++i) {
                const float* rowp = &xs[ch * 1152 + (r + i) * 36];
                float xr[32];
                #pragma unroll
                for (int m = 0; m < 8; ++m) {
                    float4 v = ((const float4*)rowp)[m];
                    xr[4*m+0] = v.x; xr[4*m+1] = v.y; xr[4*m+2] = v.z; xr[4*m+3] = v.w;
                }
                float4 wj[6];
                #pragma unroll
                for (int j = 0; j < 6; ++j)
                    wj[j] = *(const float4*)&wls[(ch * 36 + i * 6 + j) * 16 + kg * 4];
                #pragma unroll
                for (int j = 0; j < 6; ++j) {
                    #pragma unroll
                    for (int c = 0; c < 27; ++c) {
                        float xv = xr[c + j];
                        acc[0][c] = fmaf(xv, wj[j].x, acc[0][c]);
                        acc[1][c] = fmaf(xv, wj[j].y, acc[1][c]);
                        acc[2][c] = fmaf(xv, wj[j].z, acc[2][c]);
                        acc[3][c] = fmaf(xv, wj[j].w, acc[3][c]);
                    }
                }
            }
        }
    }

    __syncthreads();   // all xs/wls reads complete before aliasing ot over them
    if (r < 27) {
        #pragma unroll
        for (int kk = 0; kk < 4; ++kk) {
            float bv = bls[kg * 4 + kk];
            float* dst = &ot[(kg * 4 + kk) * 729 + r * 27];
            #pragma unroll
            for (int c = 0; c < 27; ++c) dst[c] = acc[kk][c] + bv;
        }
    }
    __syncthreads();

    // single coalesced store phase: 2916 float4 per stream (frame*FEAT is 16B-aligned)
    const float4* src4 = (const float4*)ot;
    float4* dc = (float4*)(out + OFF_CONV + (size_t)frame * FEAT);
    float4* df = (float4*)(out + OFF_FLAT + (size_t)frame * FEAT);
    for (int e = tid; e < 2916; e += 128) {
        float4 v = src4[e];
        dc[e] = v;
        float4 rv;
        rv.x = v.x > 0.f ? v.x : 0.f;
        rv.y = v.y > 0.f ? v.y : 0.f;
        rv.z = v.z > 0.f ? v.z : 0.f;
        rv.w = v.w > 0.f ? v.w : 0.f;
        df[e] = rv;
    }
}

// ---------------- K2: fused adaptive scan + x@w_ih^T projection (MFMA) ----------------
// grid = 32 b * 16 f-blocks (729 feats each); block = 256 threads (4 waves).
// v2: software-prefetch — tile 0's 48 loads are issued before Bw staging; tile
// t+1's loads are issued right after the A-write barrier so they stay in flight
// under the MFMA (lgkmcnt-only) + reduce phases instead of stalling each tile.
typedef short bf16x8 __attribute__((ext_vector_type(8)));
typedef float f32x4  __attribute__((ext_vector_type(4)));

__global__ __launch_bounds__(256) void k_adapt_proj(const float* __restrict__ flat,
                                                    const float* __restrict__ w_ih,
                                                    float* __restrict__ partial)
{
    __shared__ __align__(16) unsigned short A[16 * 744];    // [t_local][f], pad->744
    __shared__ __align__(16) unsigned short Bw[16 * 744];   // [u][f] (= B^T rows)
    __shared__ __align__(16) float accscr[4 * 64 * 4];
    const int tid = threadIdx.x;
    const int b  = blockIdx.x >> 4;
    const int fb = blockIdx.x & 15;
    const int fbase = fb * 729;

    float v0[16], v1[16], v2[16];
    const float* src0 = flat + (size_t)(b * 64) * FEAT + fbase + tid * 3;
    if (tid < 243) {
        #pragma unroll
        for (int tl = 0; tl < 16; ++tl) {   // tile 0 prefetch: overlaps Bw staging
            const float* p = src0 + (size_t)tl * FEAT;
            v0[tl] = p[0]; v1[tl] = p[1]; v2[tl] = p[2];
        }
    }

    for (int n = 0; n < 16; ++n) {
        const float* src = w_ih + (size_t)n * FEAT + fbase;
        for (int f = tid; f < 729; f += 256) Bw[n * 744 + f] = f2bf(src[f]);
    }
    if (tid < 240) {
        int n = tid / 15, c = 729 + (tid % 15);
        A[n * 744 + c]  = 0;
        Bw[n * 744 + c] = 0;
    }
    __syncthreads();

    float ad0 = 0.f, ad1 = 0.f, ad2 = 0.f;  // adapt state for this thread's 3 feats
    const int w = tid >> 6, l = tid & 63;
    const int m = l & 15, q = l >> 4;       // MFMA lane decomposition

    for (int tt = 0; tt < 4; ++tt) {
        if (tid < 243) {
            unsigned short* arow = &A[tid * 3];
            #pragma unroll
            for (int tl = 0; tl < 16; ++tl) {
                float o0 = fmaxf(v0[tl] - ad0, 0.f); ad0 = (ad0 + 0.1f * o0) * 0.9f;
                float o1 = fmaxf(v1[tl] - ad1, 0.f); ad1 = (ad1 + 0.1f * o1) * 0.9f;
                float o2 = fmaxf(v2[tl] - ad2, 0.f); ad2 = (ad2 + 0.1f * o2) * 0.9f;
                unsigned short* dst = arow + tl * 744;
                dst[0] = f2bf(o0); dst[1] = f2bf(o1); dst[2] = f2bf(o2);
            }
        }
        __syncthreads();

        // prefetch next tile: stays in flight across MFMA (LDS-only) + reduce
        if (tt < 3 && tid < 243) {
            const float* srcn = flat + (size_t)(b * 64 + (tt + 1) * 16) * FEAT + fbase + tid * 3;
            #pragma unroll
            for (int tl = 0; tl < 16; ++tl) {
                const float* p = srcn + (size_t)tl * FEAT;
                v0[tl] = p[0]; v1[tl] = p[1]; v2[tl] = p[2];
            }
        }

        f32x4 acc = {0.f, 0.f, 0.f, 0.f};
        for (int s = w; s < 23; s += 4) {   // 736 = 23*32 K-steps, zero-padded tail
            int k0 = s * 32;
            bf16x8 av = *(const bf16x8*)&A [m * 744 + k0 + q * 8];
            bf16x8 bv = *(const bf16x8*)&Bw[m * 744 + k0 + q * 8];
            acc = __builtin_amdgcn_mfma_f32_16x16x32_bf16(av, bv, acc, 0, 0, 0);
        }
        *(f32x4*)&accscr[(w * 64 + l) * 4] = acc;
        __syncthreads();
        {
            int ll = tid >> 2, rg = tid & 3;
            float s = accscr[(0 * 64 + ll) * 4 + rg] + accscr[(1 * 64 + ll) * 4 + rg]
                    + accscr[(2 * 64 + ll) * 4 + rg] + accscr[(3 * 64 + ll) * 4 + rg];
            int row = ((ll >> 4) * 4) + rg;   // t_local  (C/D: row=(lane>>4)*4+reg)
            int col = ll & 15;                // u        (C/D: col=lane&15)
            partial[(size_t)(((fb * 32 + b) * 64 + tt * 16 + row) * 16) + col] = s;
        }
        __syncthreads();
    }
}

// ---------------- K3: sum partials + SimpleRNN (with adaptation) + FC ----------------
// grid = 8 blocks * 64 threads (1 wave): lanes = (bl 0..3, u 0..15), b = blk*4+bl.
__global__ __launch_bounds__(64) void k_rnn(const float* __restrict__ partial,
                                            const float* __restrict__ w_hh,
                                            const float* __restrict__ b_ih,
                                            const float* __restrict__ b_hh,
                                            const float* __restrict__ fc_w,
                                            const float* __restrict__ fc_b,
                                            float* __restrict__ out)
{
    __shared__ __align__(16) float preL[4096];   // [bl][t][u]
    __shared__ float hL[64];                     // [bl][u]
    const int l = threadIdx.x;
    const int bl = l >> 4, u = l & 15;
    const int b = blockIdx.x * 4 + bl;

    const float4* p4 = (const float4*)partial;   // 8192 float4 per fb slab
    float4* pl4 = (float4*)preL;
    for (int c = l; c < 1024; c += 64) {
        float4 s = {0.f, 0.f, 0.f, 0.f};
        for (int fb = 0; fb < 16; ++fb) {
            float4 v = p4[(size_t)fb * 8192 + blockIdx.x * 1024 + c];
            s.x += v.x; s.y += v.y; s.z += v.z; s.w += v.w;
        }
        pl4[c] = s;
    }

    float wv[16];
    #pragma unroll
    for (int mm = 0; mm < 4; ++mm) {
        float4 t4 = *(const float4*)(w_hh + u * 16 + mm * 4);
        wv[4*mm+0] = t4.x; wv[4*mm+1] = t4.y; wv[4*mm+2] = t4.z; wv[4*mm+3] = t4.w;
    }
    const float bsum = b_ih[u] + b_hh[u];
    float frow[16]; float fcb = 0.f;
    if (u < 2) {
        #pragma unroll
        for (int mm = 0; mm < 4; ++mm) {
            float4 t4 = *(const float4*)(fc_w + u * 16 + mm * 4);
            frow[4*mm+0] = t4.x; frow[4*mm+1] = t4.y; frow[4*mm+2] = t4.z; frow[4*mm+3] = t4.w;
        }
        fcb = fc_b[u];
    }
    hL[l] = 0.f;
    float ad = 0.f;
    __syncthreads();

    for (int t = 0; t < 64; ++t) {
        float hv[16];
        #pragma unroll
        for (int mm = 0; mm < 4; ++mm) {
            float4 h4 = *(const float4*)&hL[bl * 16 + mm * 4];
            hv[4*mm+0] = h4.x; hv[4*mm+1] = h4.y; hv[4*mm+2] = h4.z; hv[4*mm+3] = h4.w;
        }
        if (t > 0 && u < 2) {   // FC for t-1 from h_{t-1}
            float fcv = fcb;
            #pragma unroll
            for (int v2 = 0; v2 < 16; ++v2) fcv = fmaf(hv[v2], frow[v2], fcv);
            out[OFF_FC + (size_t)(b * 64 + (t - 1)) * 2 + u] = fcv;
        }
        float dot = 0.f;
        #pragma unroll
        for (int v2 = 0; v2 < 16; ++v2) dot = fmaf(hv[v2], wv[v2], dot);
        float v = preL[(bl * 64 + t) * 16 + u] + bsum + dot;
        float a = v - ad; a = a > 0.f ? a : 0.f;   // relu(pre - adapt); h = relu(a) = a
        ad = (ad + 0.4f * a) * 0.9f;
        out[OFF_RNN + (size_t)(b * 64 + t) * 16 + u] = a;
        __syncthreads();
        hL[l] = a;
        __syncthreads();
    }
    {   // FC for t = 63
        float hv[16];
        #pragma unroll
        for (int mm = 0; mm < 4; ++mm) {
            float4 h4 = *(const float4*)&hL[bl * 16 + mm * 4];
            hv[4*mm+0] = h4.x; hv[4*mm+1] = h4.y; hv[4*mm+2] = h4.z; hv[4*mm+3] = h4.w;
        }
        if (u < 2) {
            float fcv = fcb;
            #pragma unroll
            for (int v2 = 0; v2 < 16; ++v2) fcv = fmaf(hv[v2], frow[v2], fcv);
            out[OFF_FC + (size_t)(b * 64 + 63) * 2 + u] = fcv;
        }
    }
}

extern "C" void kernel_launch(void* const* d_in, const int* in_sizes, int n_in,
                              void* d_out, int out_size, void* d_ws, size_t ws_size,
                              hipStream_t stream)
{
    const float* x    = (const float*)d_in[0];
    const float* cw   = (const float*)d_in[1];
    const float* cb   = (const float*)d_in[2];
    const float* w_ih = (const float*)d_in[3];
    const float* w_hh = (const float*)d_in[4];
    const float* b_ih = (const float*)d_in[5];
    const float* b_hh = (const float*)d_in[6];
    const float* fc_w = (const float*)d_in[7];
    const float* fc_b = (const float*)d_in[8];
    float* out = (float*)d_out;
    float* partial = (float*)d_ws;   // 16 fb * 32 b * 64 t * 16 u fp32 = 2 MB

    k_conv<<<2048, 128, 0, stream>>>(x, cw, cb, out);
    k_adapt_proj<<<512, 256, 0, stream>>>(out + OFF_FLAT, w_ih, partial);
    k_rnn<<<8, 64, 0, stream>>>(partial, w_hh, b_ih, b_hh, fc_w, fc_b, out);
}

// Round 2
// 316.194 us; speedup vs baseline: 1.1015x; 1.1015x over previous
//
#include <hip/hip_runtime.h>

// ---------------- problem constants ----------------
// Inputs float32; d_out float32. Concat: fc, conv, flat, rnn.
#define FEAT 11664           // 16 * 27 * 27
#define OFF_FC   0u
#define OFF_CONV 4096u
#define OFF_FLAT 23891968u   // 4096 + 2048*11664
#define OFF_RNN  47779840u   // OFF_FLAT + 2048*11664

static __device__ __forceinline__ unsigned short f2bf(float f) {
    unsigned int u = __float_as_uint(f);
    u += 0x7FFFu + ((u >> 16) & 1u);       // round-to-nearest-even
    return (unsigned short)(u >> 16);
}

// ---------------- K1: conv + bias -> out_conv ; relu -> out_flat ----------------
// grid = 2048 frames (b*64+t), block = 128 = (kg 0..3)*(r 0..31, active r<27).
// (unchanged from round 1 — kept as control)
__global__ __launch_bounds__(128) void k_conv(const float* __restrict__ x,
                                              const float* __restrict__ cw,
                                              const float* __restrict__ cb,
                                              float* __restrict__ out)
{
    __shared__ __align__(16) float smem[11664];  // xs(2304)+wls(1152) compute; ot(11664) epilogue
    __shared__ float bls[16];
    float* xs  = smem;          // [ch(2)][row(32)][col(36 padded)]
    float* wls = smem + 2304;   // [ch*36 + i*6 + j][k(16)]
    float* ot  = smem;          // [k(16)][r(27)][c(27)] full-frame epilogue tile
    const int tid = threadIdx.x;
    const int frame = blockIdx.x;

    const float4* xg = (const float4*)(x + (size_t)frame * 2048);
    for (int c0 = tid; c0 < 512; c0 += 128) {
        float4 v = xg[c0];
        int e0 = c0 * 4;
        int ch = e0 >> 10, rem = e0 & 1023, row = rem >> 5, col = rem & 31;
        float* dst = &xs[ch * 1152 + row * 36 + col];
        dst[0] = v.x; dst[1] = v.y; dst[2] = v.z; dst[3] = v.w;
    }
    for (int idx = tid; idx < 1152; idx += 128) {
        int k = idx / 72;
        int rem = idx - k * 72;
        wls[rem * 16 + k] = cw[idx];
    }
    if (tid < 16) bls[tid] = cb[tid];
    __syncthreads();

    const int kg = tid >> 5;
    const int r  = tid & 31;
    float acc[4][27];
    if (r < 27) {
        #pragma unroll
        for (int kk = 0; kk < 4; ++kk)
            #pragma unroll
            for (int c = 0; c < 27; ++c) acc[kk][c] = 0.f;

        for (int ch = 0; ch < 2; ++ch) {
            for (int i = 0; i < 6; ++i) {
                const float* rowp = &xs[ch * 1152 + (r + i) * 36];
                float xr[32];
                #pragma unroll
                for (int m = 0; m < 8; ++m) {
                    float4 v = ((const float4*)rowp)[m];
                    xr[4*m+0] = v.x; xr[4*m+1] = v.y; xr[4*m+2] = v.z; xr[4*m+3] = v.w;
                }
                float4 wj[6];
                #pragma unroll
                for (int j = 0; j < 6; ++j)
                    wj[j] = *(const float4*)&wls[(ch * 36 + i * 6 + j) * 16 + kg * 4];
                #pragma unroll
                for (int j = 0; j < 6; ++j) {
                    #pragma unroll
                    for (int c = 0; c < 27; ++c) {
                        float xv = xr[c + j];
                        acc[0][c] = fmaf(xv, wj[j].x, acc[0][c]);
                        acc[1][c] = fmaf(xv, wj[j].y, acc[1][c]);
                        acc[2][c] = fmaf(xv, wj[j].z, acc[2][c]);
                        acc[3][c] = fmaf(xv, wj[j].w, acc[3][c]);
                    }
                }
            }
        }
    }

    __syncthreads();   // all xs/wls reads complete before aliasing ot over them
    if (r < 27) {
        #pragma unroll
        for (int kk = 0; kk < 4; ++kk) {
            float bv = bls[kg * 4 + kk];
            float* dst = &ot[(kg * 4 + kk) * 729 + r * 27];
            #pragma unroll
            for (int c = 0; c < 27; ++c) dst[c] = acc[kk][c] + bv;
        }
    }
    __syncthreads();

    // single coalesced store phase: 2916 float4 per stream (frame*FEAT is 16B-aligned)
    const float4* src4 = (const float4*)ot;
    float4* dc = (float4*)(out + OFF_CONV + (size_t)frame * FEAT);
    float4* df = (float4*)(out + OFF_FLAT + (size_t)frame * FEAT);
    for (int e = tid; e < 2916; e += 128) {
        float4 v = src4[e];
        dc[e] = v;
        float4 rv;
        rv.x = v.x > 0.f ? v.x : 0.f;
        rv.y = v.y > 0.f ? v.y : 0.f;
        rv.z = v.z > 0.f ? v.z : 0.f;
        rv.w = v.w > 0.f ? v.w : 0.f;
        df[e] = rv;
    }
}

// ---------------- K2 (48-slab): fused adaptive scan + x@w_ih^T (MFMA) ----------------
// grid = 32 b * 48 f-slices (243 feats each); block = 256 threads (4 waves).
// ~21 KB LDS, low VGPR -> ~5-6 blocks/CU (vs 2 for the 16-slab variant): blocks
// pipeline across each other, hiding the per-block serial phase chain.
// LDS row stride 264 u16 (528 B): lane m step = 4 banks -> 2-way conflict (free).
typedef short bf16x8 __attribute__((ext_vector_type(8)));
typedef float f32x4  __attribute__((ext_vector_type(4)));

__global__ __launch_bounds__(256) void k_adapt_proj48(const float* __restrict__ flat,
                                                      const float* __restrict__ w_ih,
                                                      float* __restrict__ partial)
{
    __shared__ __align__(16) unsigned short A[16 * 264];    // [t_local][f], pad 243->264
    __shared__ __align__(16) unsigned short Bw[16 * 264];   // [u][f]
    __shared__ __align__(16) float accscr[4 * 64 * 4];
    const int tid = threadIdx.x;
    const int b  = blockIdx.x / 48;
    const int fb = blockIdx.x % 48;
    const int fbase = fb * 243;

    float v[16];
    if (tid < 243) {          // tile-0 prefetch: overlaps Bw staging
        const float* p0 = flat + (size_t)(b * 64) * FEAT + fbase + tid;
        #pragma unroll
        for (int tl = 0; tl < 16; ++tl) v[tl] = p0[(size_t)tl * FEAT];
    }

    for (int n = 0; n < 16; ++n) {
        if (tid < 243) Bw[n * 264 + tid] = f2bf(w_ih[(size_t)n * FEAT + fbase + tid]);
    }
    if (tid < 208) {          // zero MFMA K-pad cols 243..255 (cols 256..263 never read)
        int n = tid / 13, c = 243 + tid % 13;
        A[n * 264 + c]  = 0;
        Bw[n * 264 + c] = 0;
    }
    __syncthreads();

    float ad = 0.f;                         // adapt state: 1 feature per thread
    const int w = tid >> 6, l = tid & 63;
    const int m = l & 15, q = l >> 4;       // MFMA lane decomposition

    for (int tt = 0; tt < 4; ++tt) {
        if (tid < 243) {
            unsigned short* arow = &A[tid];
            #pragma unroll
            for (int tl = 0; tl < 16; ++tl) {
                float o = fmaxf(v[tl] - ad, 0.f); ad = (ad + 0.1f * o) * 0.9f;
                arow[tl * 264] = f2bf(o);
            }
        }
        __syncthreads();

        if (tt < 3 && tid < 243) {          // prefetch next tile under MFMA+reduce
            const float* pn = flat + (size_t)(b * 64 + (tt + 1) * 16) * FEAT + fbase + tid;
            #pragma unroll
            for (int tl = 0; tl < 16; ++tl) v[tl] = pn[(size_t)tl * FEAT];
        }

        f32x4 acc = {0.f, 0.f, 0.f, 0.f};
        #pragma unroll
        for (int s = w; s < 8; s += 4) {    // 256 = 8*32 K-steps, zero-padded tail
            int k0 = s * 32;
            bf16x8 av = *(const bf16x8*)&A [m * 264 + k0 + q * 8];
            bf16x8 bv = *(const bf16x8*)&Bw[m * 264 + k0 + q * 8];
            acc = __builtin_amdgcn_mfma_f32_16x16x32_bf16(av, bv, acc, 0, 0, 0);
        }
        *(f32x4*)&accscr[(w * 64 + l) * 4] = acc;
        __syncthreads();
        {
            int ll = tid >> 2, rg = tid & 3;
            float s = accscr[(0 * 64 + ll) * 4 + rg] + accscr[(1 * 64 + ll) * 4 + rg]
                    + accscr[(2 * 64 + ll) * 4 + rg] + accscr[(3 * 64 + ll) * 4 + rg];
            int row = ((ll >> 4) * 4) + rg;   // t_local  (C/D: row=(lane>>4)*4+reg)
            int col = ll & 15;                // u        (C/D: col=lane&15)
            partial[(size_t)(((fb * 32 + b) * 64 + tt * 16 + row) * 16) + col] = s;
        }
        __syncthreads();
    }
}

// ---------------- K2 (16-slab fallback, ws too small): round-1 kernel ----------------
__global__ __launch_bounds__(256) void k_adapt_proj16(const float* __restrict__ flat,
                                                      const float* __restrict__ w_ih,
                                                      float* __restrict__ partial)
{
    __shared__ __align__(16) unsigned short A[16 * 744];
    __shared__ __align__(16) unsigned short Bw[16 * 744];
    __shared__ __align__(16) float accscr[4 * 64 * 4];
    const int tid = threadIdx.x;
    const int b  = blockIdx.x >> 4;
    const int fb = blockIdx.x & 15;
    const int fbase = fb * 729;

    float v0[16], v1[16], v2[16];
    const float* src0 = flat + (size_t)(b * 64) * FEAT + fbase + tid * 3;
    if (tid < 243) {
        #pragma unroll
        for (int tl = 0; tl < 16; ++tl) {
            const float* p = src0 + (size_t)tl * FEAT;
            v0[tl] = p[0]; v1[tl] = p[1]; v2[tl] = p[2];
        }
    }

    for (int n = 0; n < 16; ++n) {
        const float* src = w_ih + (size_t)n * FEAT + fbase;
        for (int f = tid; f < 729; f += 256) Bw[n * 744 + f] = f2bf(src[f]);
    }
    if (tid < 240) {
        int n = tid / 15, c = 729 + (tid % 15);
        A[n * 744 + c]  = 0;
        Bw[n * 744 + c] = 0;
    }
    __syncthreads();

    float ad0 = 0.f, ad1 = 0.f, ad2 = 0.f;
    const int w = tid >> 6, l = tid & 63;
    const int m = l & 15, q = l >> 4;

    for (int tt = 0; tt < 4; ++tt) {
        if (tid < 243) {
            unsigned short* arow = &A[tid * 3];
            #pragma unroll
            for (int tl = 0; tl < 16; ++tl) {
                float o0 = fmaxf(v0[tl] - ad0, 0.f); ad0 = (ad0 + 0.1f * o0) * 0.9f;
                float o1 = fmaxf(v1[tl] - ad1, 0.f); ad1 = (ad1 + 0.1f * o1) * 0.9f;
                float o2 = fmaxf(v2[tl] - ad2, 0.f); ad2 = (ad2 + 0.1f * o2) * 0.9f;
                unsigned short* dst = arow + tl * 744;
                dst[0] = f2bf(o0); dst[1] = f2bf(o1); dst[2] = f2bf(o2);
            }
        }
        __syncthreads();

        if (tt < 3 && tid < 243) {
            const float* srcn = flat + (size_t)(b * 64 + (tt + 1) * 16) * FEAT + fbase + tid * 3;
            #pragma unroll
            for (int tl = 0; tl < 16; ++tl) {
                const float* p = srcn + (size_t)tl * FEAT;
                v0[tl] = p[0]; v1[tl] = p[1]; v2[tl] = p[2];
            }
        }

        f32x4 acc = {0.f, 0.f, 0.f, 0.f};
        for (int s = w; s < 23; s += 4) {
            int k0 = s * 32;
            bf16x8 av = *(const bf16x8*)&A [m * 744 + k0 + q * 8];
            bf16x8 bv = *(const bf16x8*)&Bw[m * 744 + k0 + q * 8];
            acc = __builtin_amdgcn_mfma_f32_16x16x32_bf16(av, bv, acc, 0, 0, 0);
        }
        *(f32x4*)&accscr[(w * 64 + l) * 4] = acc;
        __syncthreads();
        {
            int ll = tid >> 2, rg = tid & 3;
            float s = accscr[(0 * 64 + ll) * 4 + rg] + accscr[(1 * 64 + ll) * 4 + rg]
                    + accscr[(2 * 64 + ll) * 4 + rg] + accscr[(3 * 64 + ll) * 4 + rg];
            int row = ((ll >> 4) * 4) + rg;
            int col = ll & 15;
            partial[(size_t)(((fb * 32 + b) * 64 + tt * 16 + row) * 16) + col] = s;
        }
        __syncthreads();
    }
}

// ---------------- K3: sum partials + SimpleRNN (with adaptation) + FC ----------------
// grid = 8 blocks * 64 threads = ONE WAVE per block: barrier-free. Cross-lane hL
// traffic is ordered by lockstep wave execution + compiler lgkmcnt on LDS aliasing;
// removing __syncthreads removes 128 vmcnt(0) store-drains per block.
template<int NFB>
__global__ __launch_bounds__(64) void k_rnn_t(const float* __restrict__ partial,
                                              const float* __restrict__ w_hh,
                                              const float* __restrict__ b_ih,
                                              const float* __restrict__ b_hh,
                                              const float* __restrict__ fc_w,
                                              const float* __restrict__ fc_b,
                                              float* __restrict__ out)
{
    __shared__ __align__(16) float preL[4096];   // [bl][t][u]
    __shared__ float hL[64];                     // [bl][u]
    const int l = threadIdx.x;
    const int bl = l >> 4, u = l & 15;
    const int b = blockIdx.x * 4 + bl;

    const float4* p4 = (const float4*)partial;   // 8192 float4 per fb slab
    float4* pl4 = (float4*)preL;
    for (int c = l; c < 1024; c += 64) {
        float4 s = {0.f, 0.f, 0.f, 0.f};
        for (int fb = 0; fb < NFB; ++fb) {
            float4 v = p4[(size_t)fb * 8192 + blockIdx.x * 1024 + c];
            s.x += v.x; s.y += v.y; s.z += v.z; s.w += v.w;
        }
        pl4[c] = s;
    }

    float wv[16];
    #pragma unroll
    for (int mm = 0; mm < 4; ++mm) {
        float4 t4 = *(const float4*)(w_hh + u * 16 + mm * 4);
        wv[4*mm+0] = t4.x; wv[4*mm+1] = t4.y; wv[4*mm+2] = t4.z; wv[4*mm+3] = t4.w;
    }
    const float bsum = b_ih[u] + b_hh[u];
    float frow[16]; float fcb = 0.f;
    if (u < 2) {
        #pragma unroll
        for (int mm = 0; mm < 4; ++mm) {
            float4 t4 = *(const float4*)(fc_w + u * 16 + mm * 4);
            frow[4*mm+0] = t4.x; frow[4*mm+1] = t4.y; frow[4*mm+2] = t4.z; frow[4*mm+3] = t4.w;
        }
        fcb = fc_b[u];
    }
    hL[l] = 0.f;
    float ad = 0.f;

    for (int t = 0; t < 64; ++t) {
        float hv[16];
        #pragma unroll
        for (int mm = 0; mm < 4; ++mm) {
            float4 h4 = *(const float4*)&hL[bl * 16 + mm * 4];
            hv[4*mm+0] = h4.x; hv[4*mm+1] = h4.y; hv[4*mm+2] = h4.z; hv[4*mm+3] = h4.w;
        }
        if (t > 0 && u < 2) {   // FC for t-1 from h_{t-1}
            float fcv = fcb;
            #pragma unroll
            for (int v2 = 0; v2 < 16; ++v2) fcv = fmaf(hv[v2], frow[v2], fcv);
            out[OFF_FC + (size_t)(b * 64 + (t - 1)) * 2 + u] = fcv;
        }
        float dot = 0.f;
        #pragma unroll
        for (int v2 = 0; v2 < 16; ++v2) dot = fmaf(hv[v2], wv[v2], dot);
        float v = preL[(bl * 64 + t) * 16 + u] + bsum + dot;
        float a = v - ad; a = a > 0.f ? a : 0.f;   // relu(pre - adapt); h = relu(a) = a
        ad = (ad + 0.4f * a) * 0.9f;
        out[OFF_RNN + (size_t)(b * 64 + t) * 16 + u] = a;
        hL[l] = a;
    }
    {   // FC for t = 63
        float hv[16];
        #pragma unroll
        for (int mm = 0; mm < 4; ++mm) {
            float4 h4 = *(const float4*)&hL[bl * 16 + mm * 4];
            hv[4*mm+0] = h4.x; hv[4*mm+1] = h4.y; hv[4*mm+2] = h4.z; hv[4*mm+3] = h4.w;
        }
        if (u < 2) {
            float fcv = fcb;
            #pragma unroll
            for (int v2 = 0; v2 < 16; ++v2) fcv = fmaf(hv[v2], frow[v2], fcv);
            out[OFF_FC + (size_t)(b * 64 + 63) * 2 + u] = fcv;
        }
    }
}

extern "C" void kernel_launch(void* const* d_in, const int* in_sizes, int n_in,
                              void* d_out, int out_size, void* d_ws, size_t ws_size,
                              hipStream_t stream)
{
    const float* x    = (const float*)d_in[0];
    const float* cw   = (const float*)d_in[1];
    const float* cb   = (const float*)d_in[2];
    const float* w_ih = (const float*)d_in[3];
    const float* w_hh = (const float*)d_in[4];
    const float* b_ih = (const float*)d_in[5];
    const float* b_hh = (const float*)d_in[6];
    const float* fc_w = (const float*)d_in[7];
    const float* fc_b = (const float*)d_in[8];
    float* out = (float*)d_out;
    float* partial = (float*)d_ws;

    k_conv<<<2048, 128, 0, stream>>>(x, cw, cb, out);

    const size_t need48 = 48ull * 32 * 64 * 16 * 4;   // 6 MB
    if (ws_size >= need48) {
        k_adapt_proj48<<<1536, 256, 0, stream>>>(out + OFF_FLAT, w_ih, partial);
        k_rnn_t<48><<<8, 64, 0, stream>>>(partial, w_hh, b_ih, b_hh, fc_w, fc_b, out);
    } else {
        k_adapt_proj16<<<512, 256, 0, stream>>>(out + OFF_FLAT, w_ih, partial);
        k_rnn_t<16><<<8, 64, 0, stream>>>(partial, w_hh, b_ih, b_hh, fc_w, fc_b, out);
    }
}

// Round 3
// 297.970 us; speedup vs baseline: 1.1689x; 1.0612x over previous
//
#include <hip/hip_runtime.h>

// ---------------- problem constants ----------------
// Inputs float32; d_out float32. Concat: fc, conv, flat, rnn.
#define FEAT 11664           // 16 * 27 * 27
#define OFF_FC   0u
#define OFF_CONV 4096u
#define OFF_FLAT 23891968u   // 4096 + 2048*11664
#define OFF_RNN  47779840u   // OFF_FLAT + 2048*11664

static __device__ __forceinline__ unsigned short f2bf(float f) {
    unsigned int u = __float_as_uint(f);
    u += 0x7FFFu + ((u >> 16) & 1u);       // round-to-nearest-even
    return (unsigned short)(u >> 16);
}

// ---------------- K1: conv + bias -> out_conv ; relu -> out_flat ----------------
// grid = CVT + 2048. Blocks [0,CVT): convert w_ih row n into zero-padded bf16
// image wb[(fb*16+n)*264 + c] (runs CONCURRENT with conv blocks, hidden under
// k1's ~50us). Blocks [CVT, CVT+2048): frame conv, unchanged from round 2.
__global__ __launch_bounds__(128) void k_conv(const float* __restrict__ x,
                                              const float* __restrict__ cw,
                                              const float* __restrict__ cb,
                                              float* __restrict__ out,
                                              const float* __restrict__ w_ih,
                                              unsigned short* __restrict__ wb,
                                              int cvt)
{
    __shared__ __align__(16) float smem[11664];  // xs(2304)+wls(1152) compute; ot(11664) epilogue
    __shared__ float bls[16];
    const int tid = threadIdx.x;

    if (blockIdx.x < (unsigned)cvt) {            // weight pre-conversion: row n
        const int n = blockIdx.x;
        const float* src = w_ih + (size_t)n * FEAT;
        for (int idx = tid; idx < 48 * 264; idx += 128) {
            int fb = idx / 264, c = idx - fb * 264;
            unsigned short v = (c < 243) ? f2bf(src[fb * 243 + c]) : (unsigned short)0;
            wb[(size_t)(fb * 16 + n) * 264 + c] = v;
        }
        return;
    }

    float* xs  = smem;          // [ch(2)][row(32)][col(36 padded)]
    float* wls = smem + 2304;   // [ch*36 + i*6 + j][k(16)]
    float* ot  = smem;          // [k(16)][r(27)][c(27)] full-frame epilogue tile
    const int frame = blockIdx.x - cvt;

    const float4* xg = (const float4*)(x + (size_t)frame * 2048);
    for (int c0 = tid; c0 < 512; c0 += 128) {
        float4 v = xg[c0];
        int e0 = c0 * 4;
        int ch = e0 >> 10, rem = e0 & 1023, row = rem >> 5, col = rem & 31;
        float* dst = &xs[ch * 1152 + row * 36 + col];
        dst[0] = v.x; dst[1] = v.y; dst[2] = v.z; dst[3] = v.w;
    }
    for (int idx = tid; idx < 1152; idx += 128) {
        int k = idx / 72;
        int rem = idx - k * 72;
        wls[rem * 16 + k] = cw[idx];
    }
    if (tid < 16) bls[tid] = cb[tid];
    __syncthreads();

    const int kg = tid >> 5;
    const int r  = tid & 31;
    float acc[4][27];
    if (r < 27) {
        #pragma unroll
        for (int kk = 0; kk < 4; ++kk)
            #pragma unroll
            for (int c = 0; c < 27; ++c) acc[kk][c] = 0.f;

        for (int ch = 0; ch < 2; ++ch) {
            for (int i = 0; i < 6; ++i) {
                const float* rowp = &xs[ch * 1152 + (r + i) * 36];
                float xr[32];
                #pragma unroll
                for (int m = 0; m < 8; ++m) {
                    float4 v = ((const float4*)rowp)[m];
                    xr[4*m+0] = v.x; xr[4*m+1] = v.y; xr[4*m+2] = v.z; xr[4*m+3] = v.w;
                }
                float4 wj[6];
                #pragma unroll
                for (int j = 0; j < 6; ++j)
                    wj[j] = *(const float4*)&wls[(ch * 36 + i * 6 + j) * 16 + kg * 4];
                #pragma unroll
                for (int j = 0; j < 6; ++j) {
                    #pragma unroll
                    for (int c = 0; c < 27; ++c) {
                        float xv = xr[c + j];
                        acc[0][c] = fmaf(xv, wj[j].x, acc[0][c]);
                        acc[1][c] = fmaf(xv, wj[j].y, acc[1][c]);
                        acc[2][c] = fmaf(xv, wj[j].z, acc[2][c]);
                        acc[3][c] = fmaf(xv, wj[j].w, acc[3][c]);
                    }
                }
            }
        }
    }

    __syncthreads();   // all xs/wls reads complete before aliasing ot over them
    if (r < 27) {
        #pragma unroll
        for (int kk = 0; kk < 4; ++kk) {
            float bv = bls[kg * 4 + kk];
            float* dst = &ot[(kg * 4 + kk) * 729 + r * 27];
            #pragma unroll
            for (int c = 0; c < 27; ++c) dst[c] = acc[kk][c] + bv;
        }
    }
    __syncthreads();

    const float4* src4 = (const float4*)ot;
    float4* dc = (float4*)(out + OFF_CONV + (size_t)frame * FEAT);
    float4* df = (float4*)(out + OFF_FLAT + (size_t)frame * FEAT);
    for (int e = tid; e < 2916; e += 128) {
        float4 v = src4[e];
        dc[e] = v;
        float4 rv;
        rv.x = v.x > 0.f ? v.x : 0.f;
        rv.y = v.y > 0.f ? v.y : 0.f;
        rv.z = v.z > 0.f ? v.z : 0.f;
        rv.w = v.w > 0.f ? v.w : 0.f;
        df[e] = rv;
    }
}

// ---------------- K2 (48-slab v2): adaptive scan + x@w_ih^T (MFMA) ----------------
// grid = 32 b * 48 f-slices (243 feats); block = 256 threads (4 waves).
// B-fragments loaded ONCE from pre-converted global bf16 (L2-hot, 32x reuse):
// no Bw LDS, no staging loop. LDS = A(8.4K)+accscr(4K) -> thread-capped 8/CU.
// 2 barriers per tt (accscr WAR covered by next tt's first barrier).
typedef short bf16x8 __attribute__((ext_vector_type(8)));
typedef float f32x4  __attribute__((ext_vector_type(4)));

__global__ __launch_bounds__(256) void k_adapt_proj48(const float* __restrict__ flat,
                                                      const unsigned short* __restrict__ wb,
                                                      float* __restrict__ partial)
{
    __shared__ __align__(16) unsigned short A[16 * 264];    // [t_local][f], pad 243->264
    __shared__ __align__(16) float accscr[4 * 64 * 4];
    const int tid = threadIdx.x;
    const int b  = blockIdx.x / 48;
    const int fb = blockIdx.x % 48;
    const int fbase = fb * 243;

    const int w = tid >> 6, l = tid & 63;
    const int m = l & 15, q = l >> 4;       // MFMA lane decomposition

    // B-fragments: loop-invariant, straight to registers (16B aligned: 264*2=528B rows)
    const unsigned short* wbp = wb + (size_t)(fb * 16) * 264;
    bf16x8 bf0 = *(const bf16x8*)&wbp[m * 264 + (w    ) * 32 + q * 8];
    bf16x8 bf1 = *(const bf16x8*)&wbp[m * 264 + (w + 4) * 32 + q * 8];

    float v[16];
    if (tid < 243) {          // tile-0 prefetch
        const float* p0 = flat + (size_t)(b * 64) * FEAT + fbase + tid;
        #pragma unroll
        for (int tl = 0; tl < 16; ++tl) v[tl] = p0[(size_t)tl * FEAT];
    }
    if (tid < 208) {          // zero MFMA K-pad cols 243..255 (never overwritten)
        int n = tid / 13, c = 243 + tid % 13;
        A[n * 264 + c] = 0;
    }
    __syncthreads();

    float ad = 0.f;                         // adapt state: 1 feature per thread

    for (int tt = 0; tt < 4; ++tt) {
        if (tid < 243) {
            unsigned short* arow = &A[tid];
            #pragma unroll
            for (int tl = 0; tl < 16; ++tl) {
                float o = fmaxf(v[tl] - ad, 0.f); ad = (ad + 0.1f * o) * 0.9f;
                arow[tl * 264] = f2bf(o);
            }
        }
        __syncthreads();                    // B1: A ready (also: prev reduce reads done)

        if (tt < 3 && tid < 243) {          // prefetch next tile under MFMA+reduce
            const float* pn = flat + (size_t)(b * 64 + (tt + 1) * 16) * FEAT + fbase + tid;
            #pragma unroll
            for (int tl = 0; tl < 16; ++tl) v[tl] = pn[(size_t)tl * FEAT];
        }

        f32x4 acc = {0.f, 0.f, 0.f, 0.f};
        {
            bf16x8 a0 = *(const bf16x8*)&A[m * 264 + (w    ) * 32 + q * 8];
            acc = __builtin_amdgcn_mfma_f32_16x16x32_bf16(a0, bf0, acc, 0, 0, 0);
            bf16x8 a1 = *(const bf16x8*)&A[m * 264 + (w + 4) * 32 + q * 8];
            acc = __builtin_amdgcn_mfma_f32_16x16x32_bf16(a1, bf1, acc, 0, 0, 0);
        }
        *(f32x4*)&accscr[(w * 64 + l) * 4] = acc;
        __syncthreads();                    // B2: accscr ready; A reads done (WAR-safe)
        {
            int ll = tid >> 2, rg = tid & 3;
            float s = accscr[(0 * 64 + ll) * 4 + rg] + accscr[(1 * 64 + ll) * 4 + rg]
                    + accscr[(2 * 64 + ll) * 4 + rg] + accscr[(3 * 64 + ll) * 4 + rg];
            int row = ((ll >> 4) * 4) + rg;   // t_local  (C/D: row=(lane>>4)*4+reg)
            int col = ll & 15;                // u        (C/D: col=lane&15)
            partial[(size_t)(((fb * 32 + b) * 64 + tt * 16 + row) * 16) + col] = s;
        }
        // no barrier: next B1 orders reduce-reads before next accscr write
    }
}

// ---------------- K2 (16-slab fallback, ws too small): round-2 kernel ----------------
__global__ __launch_bounds__(256) void k_adapt_proj16(const float* __restrict__ flat,
                                                      const float* __restrict__ w_ih,
                                                      float* __restrict__ partial)
{
    __shared__ __align__(16) unsigned short A[16 * 744];
    __shared__ __align__(16) unsigned short Bw[16 * 744];
    __shared__ __align__(16) float accscr[4 * 64 * 4];
    const int tid = threadIdx.x;
    const int b  = blockIdx.x >> 4;
    const int fb = blockIdx.x & 15;
    const int fbase = fb * 729;

    float v0[16], v1[16], v2[16];
    const float* src0 = flat + (size_t)(b * 64) * FEAT + fbase + tid * 3;
    if (tid < 243) {
        #pragma unroll
        for (int tl = 0; tl < 16; ++tl) {
            const float* p = src0 + (size_t)tl * FEAT;
            v0[tl] = p[0]; v1[tl] = p[1]; v2[tl] = p[2];
        }
    }

    for (int n = 0; n < 16; ++n) {
        const float* src = w_ih + (size_t)n * FEAT + fbase;
        for (int f = tid; f < 729; f += 256) Bw[n * 744 + f] = f2bf(src[f]);
    }
    if (tid < 240) {
        int n = tid / 15, c = 729 + (tid % 15);
        A[n * 744 + c]  = 0;
        Bw[n * 744 + c] = 0;
    }
    __syncthreads();

    float ad0 = 0.f, ad1 = 0.f, ad2 = 0.f;
    const int w = tid >> 6, l = tid & 63;
    const int m = l & 15, q = l >> 4;

    for (int tt = 0; tt < 4; ++tt) {
        if (tid < 243) {
            unsigned short* arow = &A[tid * 3];
            #pragma unroll
            for (int tl = 0; tl < 16; ++tl) {
                float o0 = fmaxf(v0[tl] - ad0, 0.f); ad0 = (ad0 + 0.1f * o0) * 0.9f;
                float o1 = fmaxf(v1[tl] - ad1, 0.f); ad1 = (ad1 + 0.1f * o1) * 0.9f;
                float o2 = fmaxf(v2[tl] - ad2, 0.f); ad2 = (ad2 + 0.1f * o2) * 0.9f;
                unsigned short* dst = arow + tl * 744;
                dst[0] = f2bf(o0); dst[1] = f2bf(o1); dst[2] = f2bf(o2);
            }
        }
        __syncthreads();

        if (tt < 3 && tid < 243) {
            const float* srcn = flat + (size_t)(b * 64 + (tt + 1) * 16) * FEAT + fbase + tid * 3;
            #pragma unroll
            for (int tl = 0; tl < 16; ++tl) {
                const float* p = srcn + (size_t)tl * FEAT;
                v0[tl] = p[0]; v1[tl] = p[1]; v2[tl] = p[2];
            }
        }

        f32x4 acc = {0.f, 0.f, 0.f, 0.f};
        for (int s = w; s < 23; s += 4) {
            int k0 = s * 32;
            bf16x8 av = *(const bf16x8*)&A [m * 744 + k0 + q * 8];
            bf16x8 bv = *(const bf16x8*)&Bw[m * 744 + k0 + q * 8];
            acc = __builtin_amdgcn_mfma_f32_16x16x32_bf16(av, bv, acc, 0, 0, 0);
        }
        *(f32x4*)&accscr[(w * 64 + l) * 4] = acc;
        __syncthreads();
        {
            int ll = tid >> 2, rg = tid & 3;
            float s = accscr[(0 * 64 + ll) * 4 + rg] + accscr[(1 * 64 + ll) * 4 + rg]
                    + accscr[(2 * 64 + ll) * 4 + rg] + accscr[(3 * 64 + ll) * 4 + rg];
            int row = ((ll >> 4) * 4) + rg;
            int col = ll & 15;
            partial[(size_t)(((fb * 32 + b) * 64 + tt * 16 + row) * 16) + col] = s;
        }
        __syncthreads();
    }
}

// ---------------- K_reduce: 48-slab partial sum -> pre[b][t][u] ----------------
// grid = 128 blocks * 256 threads: one float4 of pre per thread. 6 MB read with
// 32K threads (vs 512 threads in old k3) -> latency fully hidden.
__global__ __launch_bounds__(256) void k_reduce(const float* __restrict__ partial,
                                                float* __restrict__ pre)
{
    const int idx = blockIdx.x * 256 + threadIdx.x;     // 0..32767 float4
    const float4* p4 = (const float4*)partial;
    float4 s = {0.f, 0.f, 0.f, 0.f};
    #pragma unroll
    for (int fb = 0; fb < 48; ++fb) {
        float4 v = p4[(size_t)fb * 8192 + idx];
        s.x += v.x; s.y += v.y; s.z += v.z; s.w += v.w;
    }
    ((float4*)pre)[idx] = s;
}

// ---------------- K3: SimpleRNN (with adaptation) + FC, from pre ----------------
// grid = 8 blocks * 64 threads = ONE WAVE per block: barrier-free.
__global__ __launch_bounds__(64) void k_rnn_pre(const float* __restrict__ pre,
                                                const float* __restrict__ w_hh,
                                                const float* __restrict__ b_ih,
                                                const float* __restrict__ b_hh,
                                                const float* __restrict__ fc_w,
                                                const float* __restrict__ fc_b,
                                                float* __restrict__ out)
{
    __shared__ __align__(16) float preL[4096];   // [bl][t][u]
    __shared__ float hL[64];                     // [bl][u]
    const int l = threadIdx.x;
    const int bl = l >> 4, u = l & 15;
    const int b = blockIdx.x * 4 + bl;

    const float4* p4 = (const float4*)pre;
    float4* pl4 = (float4*)preL;
    for (int c = l; c < 1024; c += 64) pl4[c] = p4[(size_t)blockIdx.x * 1024 + c];

    float wv[16];
    #pragma unroll
    for (int mm = 0; mm < 4; ++mm) {
        float4 t4 = *(const float4*)(w_hh + u * 16 + mm * 4);
        wv[4*mm+0] = t4.x; wv[4*mm+1] = t4.y; wv[4*mm+2] = t4.z; wv[4*mm+3] = t4.w;
    }
    const float bsum = b_ih[u] + b_hh[u];
    float frow[16]; float fcb = 0.f;
    if (u < 2) {
        #pragma unroll
        for (int mm = 0; mm < 4; ++mm) {
            float4 t4 = *(const float4*)(fc_w + u * 16 + mm * 4);
            frow[4*mm+0] = t4.x; frow[4*mm+1] = t4.y; frow[4*mm+2] = t4.z; frow[4*mm+3] = t4.w;
        }
        fcb = fc_b[u];
    }
    hL[l] = 0.f;
    float ad = 0.f;

    for (int t = 0; t < 64; ++t) {
        float hv[16];
        #pragma unroll
        for (int mm = 0; mm < 4; ++mm) {
            float4 h4 = *(const float4*)&hL[bl * 16 + mm * 4];
            hv[4*mm+0] = h4.x; hv[4*mm+1] = h4.y; hv[4*mm+2] = h4.z; hv[4*mm+3] = h4.w;
        }
        if (t > 0 && u < 2) {
            float fcv = fcb;
            #pragma unroll
            for (int v2 = 0; v2 < 16; ++v2) fcv = fmaf(hv[v2], frow[v2], fcv);
            out[OFF_FC + (size_t)(b * 64 + (t - 1)) * 2 + u] = fcv;
        }
        float dot = 0.f;
        #pragma unroll
        for (int v2 = 0; v2 < 16; ++v2) dot = fmaf(hv[v2], wv[v2], dot);
        float v = preL[(bl * 64 + t) * 16 + u] + bsum + dot;
        float a = v - ad; a = a > 0.f ? a : 0.f;
        ad = (ad + 0.4f * a) * 0.9f;
        out[OFF_RNN + (size_t)(b * 64 + t) * 16 + u] = a;
        hL[l] = a;
    }
    {
        float hv[16];
        #pragma unroll
        for (int mm = 0; mm < 4; ++mm) {
            float4 h4 = *(const float4*)&hL[bl * 16 + mm * 4];
            hv[4*mm+0] = h4.x; hv[4*mm+1] = h4.y; hv[4*mm+2] = h4.z; hv[4*mm+3] = h4.w;
        }
        if (u < 2) {
            float fcv = fcb;
            #pragma unroll
            for (int v2 = 0; v2 < 16; ++v2) fcv = fmaf(hv[v2], frow[v2], fcv);
            out[OFF_FC + (size_t)(b * 64 + 63) * 2 + u] = fcv;
        }
    }
}

// ---------------- K3 fallback (16-slab, inline reduce): round-2 kernel ----------------
__global__ __launch_bounds__(64) void k_rnn16(const float* __restrict__ partial,
                                              const float* __restrict__ w_hh,
                                              const float* __restrict__ b_ih,
                                              const float* __restrict__ b_hh,
                                              const float* __restrict__ fc_w,
                                              const float* __restrict__ fc_b,
                                              float* __restrict__ out)
{
    __shared__ __align__(16) float preL[4096];
    __shared__ float hL[64];
    const int l = threadIdx.x;
    const int bl = l >> 4, u = l & 15;
    const int b = blockIdx.x * 4 + bl;

    const float4* p4 = (const float4*)partial;
    float4* pl4 = (float4*)preL;
    for (int c = l; c < 1024; c += 64) {
        float4 s = {0.f, 0.f, 0.f, 0.f};
        for (int fb = 0; fb < 16; ++fb) {
            float4 v = p4[(size_t)fb * 8192 + blockIdx.x * 1024 + c];
            s.x += v.x; s.y += v.y; s.z += v.z; s.w += v.w;
        }
        pl4[c] = s;
    }

    float wv[16];
    #pragma unroll
    for (int mm = 0; mm < 4; ++mm) {
        float4 t4 = *(const float4*)(w_hh + u * 16 + mm * 4);
        wv[4*mm+0] = t4.x; wv[4*mm+1] = t4.y; wv[4*mm+2] = t4.z; wv[4*mm+3] = t4.w;
    }
    const float bsum = b_ih[u] + b_hh[u];
    float frow[16]; float fcb = 0.f;
    if (u < 2) {
        #pragma unroll
        for (int mm = 0; mm < 4; ++mm) {
            float4 t4 = *(const float4*)(fc_w + u * 16 + mm * 4);
            frow[4*mm+0] = t4.x; frow[4*mm+1] = t4.y; frow[4*mm+2] = t4.z; frow[4*mm+3] = t4.w;
        }
        fcb = fc_b[u];
    }
    hL[l] = 0.f;
    float ad = 0.f;

    for (int t = 0; t < 64; ++t) {
        float hv[16];
        #pragma unroll
        for (int mm = 0; mm < 4; ++mm) {
            float4 h4 = *(const float4*)&hL[bl * 16 + mm * 4];
            hv[4*mm+0] = h4.x; hv[4*mm+1] = h4.y; hv[4*mm+2] = h4.z; hv[4*mm+3] = h4.w;
        }
        if (t > 0 && u < 2) {
            float fcv = fcb;
            #pragma unroll
            for (int v2 = 0; v2 < 16; ++v2) fcv = fmaf(hv[v2], frow[v2], fcv);
            out[OFF_FC + (size_t)(b * 64 + (t - 1)) * 2 + u] = fcv;
        }
        float dot = 0.f;
        #pragma unroll
        for (int v2 = 0; v2 < 16; ++v2) dot = fmaf(hv[v2], wv[v2], dot);
        float v = preL[(bl * 64 + t) * 16 + u] + bsum + dot;
        float a = v - ad; a = a > 0.f ? a : 0.f;
        ad = (ad + 0.4f * a) * 0.9f;
        out[OFF_RNN + (size_t)(b * 64 + t) * 16 + u] = a;
        hL[l] = a;
    }
    {
        float hv[16];
        #pragma unroll
        for (int mm = 0; mm < 4; ++mm) {
            float4 h4 = *(const float4*)&hL[bl * 16 + mm * 4];
            hv[4*mm+0] = h4.x; hv[4*mm+1] = h4.y; hv[4*mm+2] = h4.z; hv[4*mm+3] = h4.w;
        }
        if (u < 2) {
            float fcv = fcb;
            #pragma unroll
            for (int v2 = 0; v2 < 16; ++v2) fcv = fmaf(hv[v2], frow[v2], fcv);
            out[OFF_FC + (size_t)(b * 64 + 63) * 2 + u] = fcv;
        }
    }
}

extern "C" void kernel_launch(void* const* d_in, const int* in_sizes, int n_in,
                              void* d_out, int out_size, void* d_ws, size_t ws_size,
                              hipStream_t stream)
{
    const float* x    = (const float*)d_in[0];
    const float* cw   = (const float*)d_in[1];
    const float* cb   = (const float*)d_in[2];
    const float* w_ih = (const float*)d_in[3];
    const float* w_hh = (const float*)d_in[4];
    const float* b_ih = (const float*)d_in[5];
    const float* b_hh = (const float*)d_in[6];
    const float* fc_w = (const float*)d_in[7];
    const float* fc_b = (const float*)d_in[8];
    float* out = (float*)d_out;

    // ws layout: partial(6291456 B) | wb16(405504 B, 16B-aligned) | pre(524288 B)
    const size_t off_wb  = 6291456;
    const size_t off_pre = off_wb + 405504;     // 6696960, 16B-aligned
    const size_t need    = off_pre + 524288;    // ~6.9 MB

    float* partial = (float*)d_ws;

    if (ws_size >= need) {
        unsigned short* wb = (unsigned short*)((char*)d_ws + off_wb);
        float* pre = (float*)((char*)d_ws + off_pre);
        k_conv<<<2064, 128, 0, stream>>>(x, cw, cb, out, w_ih, wb, 16);
        k_adapt_proj48<<<1536, 256, 0, stream>>>(out + OFF_FLAT, wb, partial);
        k_reduce<<<128, 256, 0, stream>>>(partial, pre);
        k_rnn_pre<<<8, 64, 0, stream>>>(pre, w_hh, b_ih, b_hh, fc_w, fc_b, out);
    } else {
        k_conv<<<2048, 128, 0, stream>>>(x, cw, cb, out, w_ih, nullptr, 0);
        k_adapt_proj16<<<512, 256, 0, stream>>>(out + OFF_FLAT, w_ih, partial);
        k_rnn16<<<8, 64, 0, stream>>>(partial, w_hh, b_ih, b_hh, fc_w, fc_b, out);
    }
}

// Round 4
// 293.030 us; speedup vs baseline: 1.1886x; 1.0169x over previous
//
#include <hip/hip_runtime.h>

// ---------------- problem constants ----------------
// Inputs float32; d_out float32. Concat: fc, conv, flat, rnn.
#define FEAT 11664           // 16 * 27 * 27
#define OFF_FC   0u
#define OFF_CONV 4096u
#define OFF_FLAT 23891968u   // 4096 + 2048*11664
#define OFF_RNN  47779840u   // OFF_FLAT + 2048*11664

static __device__ __forceinline__ unsigned short f2bf(float f) {
    unsigned int u = __float_as_uint(f);
    u += 0x7FFFu + ((u >> 16) & 1u);       // round-to-nearest-even
    return (unsigned short)(u >> 16);
}

// ---------------- K1: conv + bias -> out_conv ; relu -> out_flat ----------------
// grid = CVT + 2048. Blocks [0,16): convert w_ih row n -> zero-padded bf16 image
// wb[(fb*16+n)*264+c]. Blocks [16,18): zero pre (128 KB) for k2's atomics. Both
// run CONCURRENT with the 2048 conv blocks (hidden under k1). Conv unchanged.
__global__ __launch_bounds__(128) void k_conv(const float* __restrict__ x,
                                              const float* __restrict__ cw,
                                              const float* __restrict__ cb,
                                              float* __restrict__ out,
                                              const float* __restrict__ w_ih,
                                              unsigned short* __restrict__ wb,
                                              float* __restrict__ pre,
                                              int cvt)
{
    __shared__ __align__(16) float smem[11664];  // xs(2304)+wls(1152) compute; ot(11664) epilogue
    __shared__ float bls[16];
    const int tid = threadIdx.x;

    if (blockIdx.x < (unsigned)cvt) {
        if (blockIdx.x < 16) {                   // weight pre-conversion: row n
            const int n = blockIdx.x;
            const float* src = w_ih + (size_t)n * FEAT;
            for (int idx = tid; idx < 48 * 264; idx += 128) {
                int fb = idx / 264, c = idx - fb * 264;
                unsigned short v = (c < 243) ? f2bf(src[fb * 243 + c]) : (unsigned short)0;
                wb[(size_t)(fb * 16 + n) * 264 + c] = v;
            }
        } else {                                 // zero pre: 8192 float4 over 2 blocks
            float4 z = {0.f, 0.f, 0.f, 0.f};
            float4* p4 = (float4*)pre;
            for (int i = (blockIdx.x - 16) * 128 + tid; i < 8192; i += 256) p4[i] = z;
        }
        return;
    }

    float* xs  = smem;          // [ch(2)][row(32)][col(36 padded)]
    float* wls = smem + 2304;   // [ch*36 + i*6 + j][k(16)]
    float* ot  = smem;          // [k(16)][r(27)][c(27)] full-frame epilogue tile
    const int frame = blockIdx.x - cvt;

    const float4* xg = (const float4*)(x + (size_t)frame * 2048);
    for (int c0 = tid; c0 < 512; c0 += 128) {
        float4 v = xg[c0];
        int e0 = c0 * 4;
        int ch = e0 >> 10, rem = e0 & 1023, row = rem >> 5, col = rem & 31;
        float* dst = &xs[ch * 1152 + row * 36 + col];
        dst[0] = v.x; dst[1] = v.y; dst[2] = v.z; dst[3] = v.w;
    }
    for (int idx = tid; idx < 1152; idx += 128) {
        int k = idx / 72;
        int rem = idx - k * 72;
        wls[rem * 16 + k] = cw[idx];
    }
    if (tid < 16) bls[tid] = cb[tid];
    __syncthreads();

    const int kg = tid >> 5;
    const int r  = tid & 31;
    float acc[4][27];
    if (r < 27) {
        #pragma unroll
        for (int kk = 0; kk < 4; ++kk)
            #pragma unroll
            for (int c = 0; c < 27; ++c) acc[kk][c] = 0.f;

        for (int ch = 0; ch < 2; ++ch) {
            for (int i = 0; i < 6; ++i) {
                const float* rowp = &xs[ch * 1152 + (r + i) * 36];
                float xr[32];
                #pragma unroll
                for (int m = 0; m < 8; ++m) {
                    float4 v = ((const float4*)rowp)[m];
                    xr[4*m+0] = v.x; xr[4*m+1] = v.y; xr[4*m+2] = v.z; xr[4*m+3] = v.w;
                }
                float4 wj[6];
                #pragma unroll
                for (int j = 0; j < 6; ++j)
                    wj[j] = *(const float4*)&wls[(ch * 36 + i * 6 + j) * 16 + kg * 4];
                #pragma unroll
                for (int j = 0; j < 6; ++j) {
                    #pragma unroll
                    for (int c = 0; c < 27; ++c) {
                        float xv = xr[c + j];
                        acc[0][c] = fmaf(xv, wj[j].x, acc[0][c]);
                        acc[1][c] = fmaf(xv, wj[j].y, acc[1][c]);
                        acc[2][c] = fmaf(xv, wj[j].z, acc[2][c]);
                        acc[3][c] = fmaf(xv, wj[j].w, acc[3][c]);
                    }
                }
            }
        }
    }

    __syncthreads();   // all xs/wls reads complete before aliasing ot over them
    if (r < 27) {
        #pragma unroll
        for (int kk = 0; kk < 4; ++kk) {
            float bv = bls[kg * 4 + kk];
            float* dst = &ot[(kg * 4 + kk) * 729 + r * 27];
            #pragma unroll
            for (int c = 0; c < 27; ++c) dst[c] = acc[kk][c] + bv;
        }
    }
    __syncthreads();

    const float4* src4 = (const float4*)ot;
    float4* dc = (float4*)(out + OFF_CONV + (size_t)frame * FEAT);
    float4* df = (float4*)(out + OFF_FLAT + (size_t)frame * FEAT);
    for (int e = tid; e < 2916; e += 128) {
        float4 v = src4[e];
        dc[e] = v;
        float4 rv;
        rv.x = v.x > 0.f ? v.x : 0.f;
        rv.y = v.y > 0.f ? v.y : 0.f;
        rv.z = v.z > 0.f ? v.z : 0.f;
        rv.w = v.w > 0.f ? v.w : 0.f;
        df[e] = rv;
    }
}

// ---------------- K2 (48-slab v3): adaptive scan + x@w_ih^T (MFMA) ----------------
// grid = 32 b * 48 f-slices (243 feats); block = 256 threads (4 waves).
// B-fragments loaded once from pre-converted global bf16. Epilogue accumulates
// DIRECTLY into pre[b][t][u] via device-scope f32 atomicAdd (pre zeroed by k1):
// deletes k_reduce kernel + 6 MB partial buffer + 12.5 MB of reduce traffic.
typedef short bf16x8 __attribute__((ext_vector_type(8)));
typedef float f32x4  __attribute__((ext_vector_type(4)));

__global__ __launch_bounds__(256) void k_adapt_proj48(const float* __restrict__ flat,
                                                      const unsigned short* __restrict__ wb,
                                                      float* __restrict__ pre)
{
    __shared__ __align__(16) unsigned short A[16 * 264];    // [t_local][f], pad 243->264
    __shared__ __align__(16) float accscr[4 * 64 * 4];
    const int tid = threadIdx.x;
    const int b  = blockIdx.x / 48;
    const int fb = blockIdx.x % 48;
    const int fbase = fb * 243;

    const int w = tid >> 6, l = tid & 63;
    const int m = l & 15, q = l >> 4;       // MFMA lane decomposition

    // B-fragments: loop-invariant, straight to registers (16B aligned: 264*2=528B rows)
    const unsigned short* wbp = wb + (size_t)(fb * 16) * 264;
    bf16x8 bf0 = *(const bf16x8*)&wbp[m * 264 + (w    ) * 32 + q * 8];
    bf16x8 bf1 = *(const bf16x8*)&wbp[m * 264 + (w + 4) * 32 + q * 8];

    float v[16];
    if (tid < 243) {          // tile-0 prefetch
        const float* p0 = flat + (size_t)(b * 64) * FEAT + fbase + tid;
        #pragma unroll
        for (int tl = 0; tl < 16; ++tl) v[tl] = p0[(size_t)tl * FEAT];
    }
    if (tid < 208) {          // zero MFMA K-pad cols 243..255 (never overwritten)
        int n = tid / 13, c = 243 + tid % 13;
        A[n * 264 + c] = 0;
    }
    __syncthreads();

    float ad = 0.f;                         // adapt state: 1 feature per thread

    for (int tt = 0; tt < 4; ++tt) {
        if (tid < 243) {
            unsigned short* arow = &A[tid];
            #pragma unroll
            for (int tl = 0; tl < 16; ++tl) {
                float o = fmaxf(v[tl] - ad, 0.f); ad = (ad + 0.1f * o) * 0.9f;
                arow[tl * 264] = f2bf(o);
            }
        }
        __syncthreads();                    // B1: A ready (also: prev reduce reads done)

        if (tt < 3 && tid < 243) {          // prefetch next tile under MFMA+reduce
            const float* pn = flat + (size_t)(b * 64 + (tt + 1) * 16) * FEAT + fbase + tid;
            #pragma unroll
            for (int tl = 0; tl < 16; ++tl) v[tl] = pn[(size_t)tl * FEAT];
        }

        f32x4 acc = {0.f, 0.f, 0.f, 0.f};
        {
            bf16x8 a0 = *(const bf16x8*)&A[m * 264 + (w    ) * 32 + q * 8];
            acc = __builtin_amdgcn_mfma_f32_16x16x32_bf16(a0, bf0, acc, 0, 0, 0);
            bf16x8 a1 = *(const bf16x8*)&A[m * 264 + (w + 4) * 32 + q * 8];
            acc = __builtin_amdgcn_mfma_f32_16x16x32_bf16(a1, bf1, acc, 0, 0, 0);
        }
        *(f32x4*)&accscr[(w * 64 + l) * 4] = acc;
        __syncthreads();                    // B2: accscr ready; A reads done (WAR-safe)
        {
            int ll = tid >> 2, rg = tid & 3;
            float s = accscr[(0 * 64 + ll) * 4 + rg] + accscr[(1 * 64 + ll) * 4 + rg]
                    + accscr[(2 * 64 + ll) * 4 + rg] + accscr[(3 * 64 + ll) * 4 + rg];
            int row = ((ll >> 4) * 4) + rg;   // t_local  (C/D: row=(lane>>4)*4+reg)
            int col = ll & 15;                // u        (C/D: col=lane&15)
            atomicAdd(&pre[(size_t)((b * 64 + tt * 16 + row) * 16) + col], s);
        }
        // no barrier: next B1 orders reduce-reads before next accscr write
    }
}

// ---------------- K2 (16-slab fallback, ws too small): round-2 kernel ----------------
__global__ __launch_bounds__(256) void k_adapt_proj16(const float* __restrict__ flat,
                                                      const float* __restrict__ w_ih,
                                                      float* __restrict__ partial)
{
    __shared__ __align__(16) unsigned short A[16 * 744];
    __shared__ __align__(16) unsigned short Bw[16 * 744];
    __shared__ __align__(16) float accscr[4 * 64 * 4];
    const int tid = threadIdx.x;
    const int b  = blockIdx.x >> 4;
    const int fb = blockIdx.x & 15;
    const int fbase = fb * 729;

    float v0[16], v1[16], v2[16];
    const float* src0 = flat + (size_t)(b * 64) * FEAT + fbase + tid * 3;
    if (tid < 243) {
        #pragma unroll
        for (int tl = 0; tl < 16; ++tl) {
            const float* p = src0 + (size_t)tl * FEAT;
            v0[tl] = p[0]; v1[tl] = p[1]; v2[tl] = p[2];
        }
    }

    for (int n = 0; n < 16; ++n) {
        const float* src = w_ih + (size_t)n * FEAT + fbase;
        for (int f = tid; f < 729; f += 256) Bw[n * 744 + f] = f2bf(src[f]);
    }
    if (tid < 240) {
        int n = tid / 15, c = 729 + (tid % 15);
        A[n * 744 + c]  = 0;
        Bw[n * 744 + c] = 0;
    }
    __syncthreads();

    float ad0 = 0.f, ad1 = 0.f, ad2 = 0.f;
    const int w = tid >> 6, l = tid & 63;
    const int m = l & 15, q = l >> 4;

    for (int tt = 0; tt < 4; ++tt) {
        if (tid < 243) {
            unsigned short* arow = &A[tid * 3];
            #pragma unroll
            for (int tl = 0; tl < 16; ++tl) {
                float o0 = fmaxf(v0[tl] - ad0, 0.f); ad0 = (ad0 + 0.1f * o0) * 0.9f;
                float o1 = fmaxf(v1[tl] - ad1, 0.f); ad1 = (ad1 + 0.1f * o1) * 0.9f;
                float o2 = fmaxf(v2[tl] - ad2, 0.f); ad2 = (ad2 + 0.1f * o2) * 0.9f;
                unsigned short* dst = arow + tl * 744;
                dst[0] = f2bf(o0); dst[1] = f2bf(o1); dst[2] = f2bf(o2);
            }
        }
        __syncthreads();

        if (tt < 3 && tid < 243) {
            const float* srcn = flat + (size_t)(b * 64 + (tt + 1) * 16) * FEAT + fbase + tid * 3;
            #pragma unroll
            for (int tl = 0; tl < 16; ++tl) {
                const float* p = srcn + (size_t)tl * FEAT;
                v0[tl] = p[0]; v1[tl] = p[1]; v2[tl] = p[2];
            }
        }

        f32x4 acc = {0.f, 0.f, 0.f, 0.f};
        for (int s = w; s < 23; s += 4) {
            int k0 = s * 32;
            bf16x8 av = *(const bf16x8*)&A [m * 744 + k0 + q * 8];
            bf16x8 bv = *(const bf16x8*)&Bw[m * 744 + k0 + q * 8];
            acc = __builtin_amdgcn_mfma_f32_16x16x32_bf16(av, bv, acc, 0, 0, 0);
        }
        *(f32x4*)&accscr[(w * 64 + l) * 4] = acc;
        __syncthreads();
        {
            int ll = tid >> 2, rg = tid & 3;
            float s = accscr[(0 * 64 + ll) * 4 + rg] + accscr[(1 * 64 + ll) * 4 + rg]
                    + accscr[(2 * 64 + ll) * 4 + rg] + accscr[(3 * 64 + ll) * 4 + rg];
            int row = ((ll >> 4) * 4) + rg;
            int col = ll & 15;
            partial[(size_t)(((fb * 32 + b) * 64 + tt * 16 + row) * 16) + col] = s;
        }
        __syncthreads();
    }
}

// ---------------- K3: SimpleRNN (with adaptation) + FC, from pre ----------------
// grid = 8 blocks * 64 threads = ONE WAVE per block: barrier-free.
__global__ __launch_bounds__(64) void k_rnn_pre(const float* __restrict__ pre,
                                                const float* __restrict__ w_hh,
                                                const float* __restrict__ b_ih,
                                                const float* __restrict__ b_hh,
                                                const float* __restrict__ fc_w,
                                                const float* __restrict__ fc_b,
                                                float* __restrict__ out)
{
    __shared__ __align__(16) float preL[4096];   // [bl][t][u]
    __shared__ float hL[64];                     // [bl][u]
    const int l = threadIdx.x;
    const int bl = l >> 4, u = l & 15;
    const int b = blockIdx.x * 4 + bl;

    const float4* p4 = (const float4*)pre;
    float4* pl4 = (float4*)preL;
    for (int c = l; c < 1024; c += 64) pl4[c] = p4[(size_t)blockIdx.x * 1024 + c];

    float wv[16];
    #pragma unroll
    for (int mm = 0; mm < 4; ++mm) {
        float4 t4 = *(const float4*)(w_hh + u * 16 + mm * 4);
        wv[4*mm+0] = t4.x; wv[4*mm+1] = t4.y; wv[4*mm+2] = t4.z; wv[4*mm+3] = t4.w;
    }
    const float bsum = b_ih[u] + b_hh[u];
    float frow[16]; float fcb = 0.f;
    if (u < 2) {
        #pragma unroll
        for (int mm = 0; mm < 4; ++mm) {
            float4 t4 = *(const float4*)(fc_w + u * 16 + mm * 4);
            frow[4*mm+0] = t4.x; frow[4*mm+1] = t4.y; frow[4*mm+2] = t4.z; frow[4*mm+3] = t4.w;
        }
        fcb = fc_b[u];
    }
    hL[l] = 0.f;
    float ad = 0.f;

    for (int t = 0; t < 64; ++t) {
        float hv[16];
        #pragma unroll
        for (int mm = 0; mm < 4; ++mm) {
            float4 h4 = *(const float4*)&hL[bl * 16 + mm * 4];
            hv[4*mm+0] = h4.x; hv[4*mm+1] = h4.y; hv[4*mm+2] = h4.z; hv[4*mm+3] = h4.w;
        }
        if (t > 0 && u < 2) {
            float fcv = fcb;
            #pragma unroll
            for (int v2 = 0; v2 < 16; ++v2) fcv = fmaf(hv[v2], frow[v2], fcv);
            out[OFF_FC + (size_t)(b * 64 + (t - 1)) * 2 + u] = fcv;
        }
        float dot = 0.f;
        #pragma unroll
        for (int v2 = 0; v2 < 16; ++v2) dot = fmaf(hv[v2], wv[v2], dot);
        float v = preL[(bl * 64 + t) * 16 + u] + bsum + dot;
        float a = v - ad; a = a > 0.f ? a : 0.f;
        ad = (ad + 0.4f * a) * 0.9f;
        out[OFF_RNN + (size_t)(b * 64 + t) * 16 + u] = a;
        hL[l] = a;
    }
    {
        float hv[16];
        #pragma unroll
        for (int mm = 0; mm < 4; ++mm) {
            float4 h4 = *(const float4*)&hL[bl * 16 + mm * 4];
            hv[4*mm+0] = h4.x; hv[4*mm+1] = h4.y; hv[4*mm+2] = h4.z; hv[4*mm+3] = h4.w;
        }
        if (u < 2) {
            float fcv = fcb;
            #pragma unroll
            for (int v2 = 0; v2 < 16; ++v2) fcv = fmaf(hv[v2], frow[v2], fcv);
            out[OFF_FC + (size_t)(b * 64 + 63) * 2 + u] = fcv;
        }
    }
}

// ---------------- K3 fallback (16-slab, inline reduce): round-2 kernel ----------------
__global__ __launch_bounds__(64) void k_rnn16(const float* __restrict__ partial,
                                              const float* __restrict__ w_hh,
                                              const float* __restrict__ b_ih,
                                              const float* __restrict__ b_hh,
                                              const float* __restrict__ fc_w,
                                              const float* __restrict__ fc_b,
                                              float* __restrict__ out)
{
    __shared__ __align__(16) float preL[4096];
    __shared__ float hL[64];
    const int l = threadIdx.x;
    const int bl = l >> 4, u = l & 15;
    const int b = blockIdx.x * 4 + bl;

    const float4* p4 = (const float4*)partial;
    float4* pl4 = (float4*)preL;
    for (int c = l; c < 1024; c += 64) {
        float4 s = {0.f, 0.f, 0.f, 0.f};
        for (int fb = 0; fb < 16; ++fb) {
            float4 v = p4[(size_t)fb * 8192 + blockIdx.x * 1024 + c];
            s.x += v.x; s.y += v.y; s.z += v.z; s.w += v.w;
        }
        pl4[c] = s;
    }

    float wv[16];
    #pragma unroll
    for (int mm = 0; mm < 4; ++mm) {
        float4 t4 = *(const float4*)(w_hh + u * 16 + mm * 4);
        wv[4*mm+0] = t4.x; wv[4*mm+1] = t4.y; wv[4*mm+2] = t4.z; wv[4*mm+3] = t4.w;
    }
    const float bsum = b_ih[u] + b_hh[u];
    float frow[16]; float fcb = 0.f;
    if (u < 2) {
        #pragma unroll
        for (int mm = 0; mm < 4; ++mm) {
            float4 t4 = *(const float4*)(fc_w + u * 16 + mm * 4);
            frow[4*mm+0] = t4.x; frow[4*mm+1] = t4.y; frow[4*mm+2] = t4.z; frow[4*mm+3] = t4.w;
        }
        fcb = fc_b[u];
    }
    hL[l] = 0.f;
    float ad = 0.f;

    for (int t = 0; t < 64; ++t) {
        float hv[16];
        #pragma unroll
        for (int mm = 0; mm < 4; ++mm) {
            float4 h4 = *(const float4*)&hL[bl * 16 + mm * 4];
            hv[4*mm+0] = h4.x; hv[4*mm+1] = h4.y; hv[4*mm+2] = h4.z; hv[4*mm+3] = h4.w;
        }
        if (t > 0 && u < 2) {
            float fcv = fcb;
            #pragma unroll
            for (int v2 = 0; v2 < 16; ++v2) fcv = fmaf(hv[v2], frow[v2], fcv);
            out[OFF_FC + (size_t)(b * 64 + (t - 1)) * 2 + u] = fcv;
        }
        float dot = 0.f;
        #pragma unroll
        for (int v2 = 0; v2 < 16; ++v2) dot = fmaf(hv[v2], wv[v2], dot);
        float v = preL[(bl * 64 + t) * 16 + u] + bsum + dot;
        float a = v - ad; a = a > 0.f ? a : 0.f;
        ad = (ad + 0.4f * a) * 0.9f;
        out[OFF_RNN + (size_t)(b * 64 + t) * 16 + u] = a;
        hL[l] = a;
    }
    {
        float hv[16];
        #pragma unroll
        for (int mm = 0; mm < 4; ++mm) {
            float4 h4 = *(const float4*)&hL[bl * 16 + mm * 4];
            hv[4*mm+0] = h4.x; hv[4*mm+1] = h4.y; hv[4*mm+2] = h4.z; hv[4*mm+3] = h4.w;
        }
        if (u < 2) {
            float fcv = fcb;
            #pragma unroll
            for (int v2 = 0; v2 < 16; ++v2) fcv = fmaf(hv[v2], frow[v2], fcv);
            out[OFF_FC + (size_t)(b * 64 + 63) * 2 + u] = fcv;
        }
    }
}

extern "C" void kernel_launch(void* const* d_in, const int* in_sizes, int n_in,
                              void* d_out, int out_size, void* d_ws, size_t ws_size,
                              hipStream_t stream)
{
    const float* x    = (const float*)d_in[0];
    const float* cw   = (const float*)d_in[1];
    const float* cb   = (const float*)d_in[2];
    const float* w_ih = (const float*)d_in[3];
    const float* w_hh = (const float*)d_in[4];
    const float* b_ih = (const float*)d_in[5];
    const float* b_hh = (const float*)d_in[6];
    const float* fc_w = (const float*)d_in[7];
    const float* fc_b = (const float*)d_in[8];
    float* out = (float*)d_out;

    // ws layout (new path): wb16(405504 B) | pre(131072 B)  -> need 536576 B
    const size_t off_pre = 405504;              // 16B-aligned
    const size_t need    = off_pre + 131072;

    if (ws_size >= need) {
        unsigned short* wb = (unsigned short*)d_ws;
        float* pre = (float*)((char*)d_ws + off_pre);
        k_conv<<<2066, 128, 0, stream>>>(x, cw, cb, out, w_ih, wb, pre, 18);
        k_adapt_proj48<<<1536, 256, 0, stream>>>(out + OFF_FLAT, wb, pre);
        k_rnn_pre<<<8, 64, 0, stream>>>(pre, w_hh, b_ih, b_hh, fc_w, fc_b, out);
    } else {
        float* partial = (float*)d_ws;           // 2 MB (16-slab fallback)
        k_conv<<<2048, 128, 0, stream>>>(x, cw, cb, out, w_ih, nullptr, nullptr, 0);
        k_adapt_proj16<<<512, 256, 0, stream>>>(out + OFF_FLAT, w_ih, partial);
        k_rnn16<<<8, 64, 0, stream>>>(partial, w_hh, b_ih, b_hh, fc_w, fc_b, out);
    }
}